// Round 1
// baseline (313.648 us; speedup 1.0000x reference)
//
#include <hip/hip_runtime.h>
#include <hip/hip_bf16.h>
#include <math.h>

typedef __bf16 bf16_t;
typedef __attribute__((ext_vector_type(8))) __bf16 bf16x8;
typedef __attribute__((ext_vector_type(4))) __bf16 bf16x4;
typedef __attribute__((ext_vector_type(4))) float f32x4;

#define B_DIM 2
#define S_DIM 2048
#define H_DIM 16
#define DK 64
#define DM 1024
#define KDIM 1024

#define MFMA(a, b, c) __builtin_amdgcn_mfma_f32_16x16x32_bf16((a), (b), (c), 0, 0, 0)

__device__ __forceinline__ void gload_lds16(const bf16_t* g, bf16_t* l) {
    __builtin_amdgcn_global_load_lds(
        (const __attribute__((address_space(1))) void*)g,
        (__attribute__((address_space(3))) void*)l, 16, 0, 0);
}

// ---------------- fp32 -> bf16 convert ----------------
__global__ void cvt_kernel(const float* __restrict__ src, bf16_t* __restrict__ dst, int n) {
    int i = (blockIdx.x * blockDim.x + threadIdx.x) * 4;
    if (i >= n) return;
    float4 v = *reinterpret_cast<const float4*>(src + i);
    bf16x4 o;
    o[0] = (__bf16)v.x; o[1] = (__bf16)v.y; o[2] = (__bf16)v.z; o[3] = (__bf16)v.w;
    *reinterpret_cast<bf16x4*>(dst + i) = o;
}

// ---------------- GEMM: Y[m,n] = sum_k A[m,k] * B[n,k]  (B^T layout) ----------------
// MODE 0: QKV projections (grid.z selects Wq/Wk/Wv; writes Q,K [B,H,S,64] and V^T [B,H,64,S], bf16)
// MODE 1: output projection (writes fp32 [M, DM])
template <int MODE>
__global__ __launch_bounds__(256)
void gemm_bt(const bf16_t* __restrict__ A,
             const bf16_t* __restrict__ B0,
             const bf16_t* __restrict__ B1,
             const bf16_t* __restrict__ B2,
             bf16_t* __restrict__ outQ,
             bf16_t* __restrict__ outK,
             bf16_t* __restrict__ outVt,
             float* __restrict__ outF) {
    __shared__ bf16_t As[128 * 32];
    __shared__ bf16_t Bs[128 * 32];

    const int t = threadIdx.x;
    const int z = blockIdx.z;
    const bf16_t* Bm = (MODE == 0) ? (z == 0 ? B0 : (z == 1 ? B1 : B2)) : B0;

    const int m0 = blockIdx.x * 128;
    const int n0 = blockIdx.y * 128;
    const int lane = t & 63;
    const int w = t >> 6;
    const int wr = w >> 1;  // 2x2 wave grid, each wave does 64x64
    const int wc = w & 1;

    f32x4 acc[4][4] = {};

    const int ar = t >> 2;         // staging row (0..63)
    const int ac = (t & 3) * 8;    // staging col (0,8,16,24)
    const bf16_t* Ag = A + (size_t)m0 * KDIM;
    const bf16_t* Bg = Bm + (size_t)n0 * KDIM;

    const int rr = lane & 15;
    const int ko = (lane >> 4) * 8;

    for (int k0 = 0; k0 < KDIM; k0 += 32) {
        gload_lds16(Ag + (size_t)ar * KDIM + k0 + ac,        &As[t * 8]);
        gload_lds16(Ag + (size_t)(ar + 64) * KDIM + k0 + ac, &As[2048 + t * 8]);
        gload_lds16(Bg + (size_t)ar * KDIM + k0 + ac,        &Bs[t * 8]);
        gload_lds16(Bg + (size_t)(ar + 64) * KDIM + k0 + ac, &Bs[2048 + t * 8]);
        __syncthreads();

        bf16x8 af[4], bfr[4];
#pragma unroll
        for (int m = 0; m < 4; ++m)
            af[m] = *reinterpret_cast<const bf16x8*>(&As[(wr * 64 + m * 16 + rr) * 32 + ko]);
#pragma unroll
        for (int n = 0; n < 4; ++n)
            bfr[n] = *reinterpret_cast<const bf16x8*>(&Bs[(wc * 64 + n * 16 + rr) * 32 + ko]);
#pragma unroll
        for (int m = 0; m < 4; ++m)
#pragma unroll
            for (int n = 0; n < 4; ++n)
                acc[m][n] = MFMA(af[m], bfr[n], acc[m][n]);
        __syncthreads();
    }

    // epilogue: C row = m0 + wr*64 + m*16 + (lane>>4)*4 + j ; col = n0 + wc*64 + n*16 + (lane&15)
    const int rbase = m0 + wr * 64 + (lane >> 4) * 4;
    const int cbase = n0 + wc * 64 + (lane & 15);
#pragma unroll
    for (int m = 0; m < 4; ++m) {
#pragma unroll
        for (int n = 0; n < 4; ++n) {
            const int gn = cbase + n * 16;
            if (MODE == 0) {
                const int h = gn >> 6, d = gn & 63;
                if (z < 2) {
                    bf16_t* dst = (z == 0) ? outQ : outK;
#pragma unroll
                    for (int j = 0; j < 4; ++j) {
                        const int gm = rbase + m * 16 + j;
                        const int b = gm >> 11, s = gm & (S_DIM - 1);
                        dst[(((size_t)(b * H_DIM + h) * S_DIM + s) << 6) + d] = (__bf16)acc[m][n][j];
                    }
                } else {
                    bf16x4 v;
#pragma unroll
                    for (int j = 0; j < 4; ++j) v[j] = (__bf16)acc[m][n][j];
                    const int gm = rbase + m * 16;
                    const int b = gm >> 11, s = gm & (S_DIM - 1);
                    *reinterpret_cast<bf16x4*>(
                        &outVt[((size_t)(b * H_DIM + h) * DK + d) * S_DIM + s]) = v;
                }
            } else {
#pragma unroll
                for (int j = 0; j < 4; ++j) {
                    const int gm = rbase + m * 16 + j;
                    outF[(size_t)gm * DM + gn] = acc[m][n][j];
                }
            }
        }
    }
}

// ---------------- RoPE (in-place on Q and K, [B,H,S,64] bf16) ----------------
__global__ void rope_kernel(bf16_t* __restrict__ Q, bf16_t* __restrict__ Kb,
                            const int* __restrict__ pos, int total) {
    int idx = blockIdx.x * blockDim.x + threadIdx.x;
    if (idx >= total) return;
    const int j = idx & 31;                 // pair index within head dim
    const int s = (idx >> 5) & (S_DIM - 1); // seq position
    const float p = (float)pos[s];
    // freq = 10000^(-2j/64) = exp2(-j * log2(10000)/32)
    const float freq = exp2f((float)j * (-13.287712379549449f / 32.0f));
    const float ang = p * freq;
    const float sn = sinf(ang), cs = cosf(ang);
    const size_t base = ((size_t)(idx >> 5) << 6) + (size_t)(j * 2);
    const float q1 = (float)Q[base], q2 = (float)Q[base + 1];
    Q[base]     = (__bf16)(q1 * cs - q2 * sn);
    Q[base + 1] = (__bf16)(q1 * sn + q2 * cs);
    const float k1 = (float)Kb[base], k2 = (float)Kb[base + 1];
    Kb[base]     = (__bf16)(k1 * cs - k2 * sn);
    Kb[base + 1] = (__bf16)(k1 * sn + k2 * cs);
}

// ---------------- causal flash attention: 1 wave per 16 q-rows ----------------
// Q,K: [B,H,S,64] bf16 (RoPE'd, Q pre-scaled here by 0.125), Vt: [B,H,64,S] bf16
// O: [B,S,H*64] bf16
__global__ __launch_bounds__(64)
void attn_kernel(const bf16_t* __restrict__ Q, const bf16_t* __restrict__ Kg,
                 const bf16_t* __restrict__ Vt, bf16_t* __restrict__ O) {
    __shared__ bf16_t P_lds[16 * 32];
    const int lane = threadIdx.x;
    const int bh = blockIdx.x >> 7;    // S/16 = 128 q-tiles per (b,h)
    const int qt = blockIdx.x & 127;
    const int q0 = qt * 16;
    const int b = bh >> 4, h = bh & 15;

    const bf16_t* Qp  = Q  + ((size_t)bh * S_DIM + q0) * DK;
    const bf16_t* Kp0 = Kg + (size_t)bh * S_DIM * DK;
    const bf16_t* Vp  = Vt + (size_t)bh * DK * S_DIM;

    const int rr = lane & 15;
    const int hi = lane >> 4;
    const int ko = hi * 8;

    bf16x8 qf0 = *reinterpret_cast<const bf16x8*>(&Qp[rr * DK + ko]);
    bf16x8 qf1 = *reinterpret_cast<const bf16x8*>(&Qp[rr * DK + 32 + ko]);
#pragma unroll
    for (int i = 0; i < 8; ++i) {  // fold 1/sqrt(64) exactly (power of two)
        qf0[i] = (__bf16)((float)qf0[i] * 0.125f);
        qf1[i] = (__bf16)((float)qf1[i] * 0.125f);
    }

    f32x4 o[4] = {};
    float mrow[4], lrow[4];
#pragma unroll
    for (int j = 0; j < 4; ++j) { mrow[j] = -INFINITY; lrow[j] = 0.0f; }

    const int nt = (q0 + 16 + 31) >> 5;  // kv tiles of 32
    for (int t = 0; t < nt; ++t) {
        const int kv0 = t * 32;
        const bf16_t* Kp = Kp0 + (size_t)kv0 * DK;
        f32x4 s0 = {}, s1 = {};
        bf16x8 kf;
        kf = *reinterpret_cast<const bf16x8*>(&Kp[rr * DK + ko]);
        s0 = MFMA(qf0, kf, s0);
        kf = *reinterpret_cast<const bf16x8*>(&Kp[rr * DK + 32 + ko]);
        s0 = MFMA(qf1, kf, s0);
        kf = *reinterpret_cast<const bf16x8*>(&Kp[(16 + rr) * DK + ko]);
        s1 = MFMA(qf0, kf, s1);
        kf = *reinterpret_cast<const bf16x8*>(&Kp[(16 + rr) * DK + 32 + ko]);
        s1 = MFMA(qf1, kf, s1);

        const int col0 = kv0 + rr, col1 = col0 + 16;
#pragma unroll
        for (int j = 0; j < 4; ++j) {
            const int row = q0 + hi * 4 + j;
            float v0 = (col0 > row) ? -INFINITY : s0[j];
            float v1 = (col1 > row) ? -INFINITY : s1[j];
            s0[j] = v0; s1[j] = v1;
            float v = fmaxf(v0, v1);
            v = fmaxf(v, __shfl_xor(v, 1, 16));
            v = fmaxf(v, __shfl_xor(v, 2, 16));
            v = fmaxf(v, __shfl_xor(v, 4, 16));
            v = fmaxf(v, __shfl_xor(v, 8, 16));
            const float mnew = fmaxf(mrow[j], v);
            const float scale = exp2f((mrow[j] - mnew) * 1.4426950408889634f);
            mrow[j] = mnew;
            const float p0 = exp2f((s0[j] - mnew) * 1.4426950408889634f);
            const float p1 = exp2f((s1[j] - mnew) * 1.4426950408889634f);
            float ps = p0 + p1;
            ps += __shfl_xor(ps, 1, 16);
            ps += __shfl_xor(ps, 2, 16);
            ps += __shfl_xor(ps, 4, 16);
            ps += __shfl_xor(ps, 8, 16);
            lrow[j] = lrow[j] * scale + ps;
#pragma unroll
            for (int g = 0; g < 4; ++g) o[g][j] *= scale;
            P_lds[(hi * 4 + j) * 32 + rr]      = (__bf16)p0;
            P_lds[(hi * 4 + j) * 32 + rr + 16] = (__bf16)p1;
        }
        __syncthreads();
        const bf16x8 pf = *reinterpret_cast<const bf16x8*>(&P_lds[rr * 32 + ko]);
#pragma unroll
        for (int g = 0; g < 4; ++g) {
            const bf16x8 vf = *reinterpret_cast<const bf16x8*>(
                &Vp[(size_t)(g * 16 + rr) * S_DIM + kv0 + ko]);
            o[g] = MFMA(pf, vf, o[g]);
        }
        __syncthreads();
    }

    float inv[4];
#pragma unroll
    for (int j = 0; j < 4; ++j) inv[j] = 1.0f / lrow[j];
#pragma unroll
    for (int g = 0; g < 4; ++g) {
        const int d = g * 16 + rr;
#pragma unroll
        for (int j = 0; j < 4; ++j) {
            const int srow = q0 + hi * 4 + j;
            O[((size_t)(b * S_DIM + srow)) * DM + h * DK + d] = (__bf16)(o[g][j] * inv[j]);
        }
    }
}

extern "C" void kernel_launch(void* const* d_in, const int* in_sizes, int n_in,
                              void* d_out, int out_size, void* d_ws, size_t ws_size,
                              hipStream_t stream) {
    const float* x  = (const float*)d_in[0];
    const float* Wq = (const float*)d_in[1];
    const float* Wk = (const float*)d_in[2];
    const float* Wv = (const float*)d_in[3];
    const float* Wo = (const float*)d_in[4];
    const int* pos  = (const int*)d_in[5];
    float* out = (float*)d_out;

    char* ws = (char*)d_ws;
    bf16_t* xb  = (bf16_t*)(ws);                  // 8 MB  [4096,1024]
    bf16_t* Wqb = (bf16_t*)(ws + (8u << 20));     // 2 MB
    bf16_t* Wkb = (bf16_t*)(ws + (10u << 20));    // 2 MB
    bf16_t* Wvb = (bf16_t*)(ws + (12u << 20));    // 2 MB
    bf16_t* Wob = (bf16_t*)(ws + (14u << 20));    // 2 MB
    bf16_t* Qb  = (bf16_t*)(ws + (16u << 20));    // 8 MB  [B,H,S,64]
    bf16_t* Kb  = (bf16_t*)(ws + (24u << 20));    // 8 MB  [B,H,S,64]
    bf16_t* Vtb = (bf16_t*)(ws + (32u << 20));    // 8 MB  [B,H,64,S]
    bf16_t* Ab  = (bf16_t*)(ws);                  // reuse xb region after QKV GEMM

    const int NX = B_DIM * S_DIM * DM;  // 4194304
    const int NW = DM * DM;             // 1048576

    cvt_kernel<<<NX / 1024, 256, 0, stream>>>(x, xb, NX);
    cvt_kernel<<<NW / 1024, 256, 0, stream>>>(Wq, Wqb, NW);
    cvt_kernel<<<NW / 1024, 256, 0, stream>>>(Wk, Wkb, NW);
    cvt_kernel<<<NW / 1024, 256, 0, stream>>>(Wv, Wvb, NW);
    cvt_kernel<<<NW / 1024, 256, 0, stream>>>(Wo, Wob, NW);

    gemm_bt<0><<<dim3(32, 8, 3), 256, 0, stream>>>(xb, Wqb, Wkb, Wvb, Qb, Kb, Vtb, nullptr);

    const int total_pairs = B_DIM * H_DIM * S_DIM * 32;  // 2097152
    rope_kernel<<<total_pairs / 256, 256, 0, stream>>>(Qb, Kb, pos, total_pairs);

    attn_kernel<<<B_DIM * H_DIM * (S_DIM / 16), 64, 0, stream>>>(Qb, Kb, Vtb, Ab);

    gemm_bt<1><<<dim3(32, 8, 1), 256, 0, stream>>>(Ab, Wob, nullptr, nullptr,
                                                   nullptr, nullptr, nullptr, out);
}

// Round 2
// 307.987 us; speedup vs baseline: 1.0184x; 1.0184x over previous
//
#include <hip/hip_runtime.h>
#include <hip/hip_bf16.h>
#include <math.h>

typedef __bf16 bf16_t;
typedef __attribute__((ext_vector_type(8))) __bf16 bf16x8;
typedef __attribute__((ext_vector_type(4))) __bf16 bf16x4;
typedef __attribute__((ext_vector_type(4))) float f32x4;

#define B_DIM 2
#define S_DIM 2048
#define H_DIM 16
#define DK 64
#define DM 1024
#define KDIM 1024

#define MFMA(a, b, c) __builtin_amdgcn_mfma_f32_16x16x32_bf16((a), (b), (c), 0, 0, 0)

__device__ __forceinline__ void gload_lds16(const bf16_t* g, bf16_t* l) {
    __builtin_amdgcn_global_load_lds(
        (const __attribute__((address_space(1))) void*)g,
        (__attribute__((address_space(3))) void*)l, 16, 0, 0);
}

// ---------------- fp32 -> bf16 convert ----------------
__global__ void cvt_kernel(const float* __restrict__ src, bf16_t* __restrict__ dst, int n) {
    int i = (blockIdx.x * blockDim.x + threadIdx.x) * 4;
    if (i >= n) return;
    float4 v = *reinterpret_cast<const float4*>(src + i);
    bf16x4 o;
    o[0] = (__bf16)v.x; o[1] = (__bf16)v.y; o[2] = (__bf16)v.z; o[3] = (__bf16)v.w;
    *reinterpret_cast<bf16x4*>(dst + i) = o;
}

// 4 weight matrices in one launch (blockIdx.y selects)
__global__ void cvt4_kernel(const float* __restrict__ s0, const float* __restrict__ s1,
                            const float* __restrict__ s2, const float* __restrict__ s3,
                            bf16_t* __restrict__ d0, bf16_t* __restrict__ d1,
                            bf16_t* __restrict__ d2, bf16_t* __restrict__ d3, int n) {
    const float* s; bf16_t* d;
    switch (blockIdx.y) {
        case 0: s = s0; d = d0; break;
        case 1: s = s1; d = d1; break;
        case 2: s = s2; d = d2; break;
        default: s = s3; d = d3; break;
    }
    int i = (blockIdx.x * blockDim.x + threadIdx.x) * 4;
    if (i >= n) return;
    float4 v = *reinterpret_cast<const float4*>(s + i);
    bf16x4 o;
    o[0] = (__bf16)v.x; o[1] = (__bf16)v.y; o[2] = (__bf16)v.z; o[3] = (__bf16)v.w;
    *reinterpret_cast<bf16x4*>(d + i) = o;
}

// ---------------- GEMM: Y[m,n] = sum_k A[m,k] * B[n,k]  (B^T layout) ----------------
template <int MODE>
__global__ __launch_bounds__(256)
void gemm_bt(const bf16_t* __restrict__ A,
             const bf16_t* __restrict__ B0,
             const bf16_t* __restrict__ B1,
             const bf16_t* __restrict__ B2,
             bf16_t* __restrict__ outQ,
             bf16_t* __restrict__ outK,
             bf16_t* __restrict__ outVt,
             float* __restrict__ outF) {
    __shared__ bf16_t As[128 * 32];
    __shared__ bf16_t Bs[128 * 32];

    const int t = threadIdx.x;
    const int z = blockIdx.z;
    const bf16_t* Bm = (MODE == 0) ? (z == 0 ? B0 : (z == 1 ? B1 : B2)) : B0;

    const int m0 = blockIdx.x * 128;
    const int n0 = blockIdx.y * 128;
    const int lane = t & 63;
    const int w = t >> 6;
    const int wr = w >> 1;
    const int wc = w & 1;

    f32x4 acc[4][4] = {};

    const int ar = t >> 2;
    const int ac = (t & 3) * 8;
    const bf16_t* Ag = A + (size_t)m0 * KDIM;
    const bf16_t* Bg = Bm + (size_t)n0 * KDIM;

    const int rr = lane & 15;
    const int ko = (lane >> 4) * 8;

    for (int k0 = 0; k0 < KDIM; k0 += 32) {
        gload_lds16(Ag + (size_t)ar * KDIM + k0 + ac,        &As[t * 8]);
        gload_lds16(Ag + (size_t)(ar + 64) * KDIM + k0 + ac, &As[2048 + t * 8]);
        gload_lds16(Bg + (size_t)ar * KDIM + k0 + ac,        &Bs[t * 8]);
        gload_lds16(Bg + (size_t)(ar + 64) * KDIM + k0 + ac, &Bs[2048 + t * 8]);
        __syncthreads();

        bf16x8 af[4], bfr[4];
#pragma unroll
        for (int m = 0; m < 4; ++m)
            af[m] = *reinterpret_cast<const bf16x8*>(&As[(wr * 64 + m * 16 + rr) * 32 + ko]);
#pragma unroll
        for (int n = 0; n < 4; ++n)
            bfr[n] = *reinterpret_cast<const bf16x8*>(&Bs[(wc * 64 + n * 16 + rr) * 32 + ko]);
#pragma unroll
        for (int m = 0; m < 4; ++m)
#pragma unroll
            for (int n = 0; n < 4; ++n)
                acc[m][n] = MFMA(af[m], bfr[n], acc[m][n]);
        __syncthreads();
    }

    const int rbase = m0 + wr * 64 + (lane >> 4) * 4;
    const int cbase = n0 + wc * 64 + (lane & 15);
#pragma unroll
    for (int m = 0; m < 4; ++m) {
#pragma unroll
        for (int n = 0; n < 4; ++n) {
            const int gn = cbase + n * 16;
            if (MODE == 0) {
                const int h = gn >> 6, d = gn & 63;
                if (z < 2) {
                    bf16_t* dst = (z == 0) ? outQ : outK;
#pragma unroll
                    for (int j = 0; j < 4; ++j) {
                        const int gm = rbase + m * 16 + j;
                        const int b = gm >> 11, s = gm & (S_DIM - 1);
                        dst[(((size_t)(b * H_DIM + h) * S_DIM + s) << 6) + d] = (__bf16)acc[m][n][j];
                    }
                } else {
                    bf16x4 v;
#pragma unroll
                    for (int j = 0; j < 4; ++j) v[j] = (__bf16)acc[m][n][j];
                    const int gm = rbase + m * 16;
                    const int b = gm >> 11, s = gm & (S_DIM - 1);
                    *reinterpret_cast<bf16x4*>(
                        &outVt[((size_t)(b * H_DIM + h) * DK + d) * S_DIM + s]) = v;
                }
            } else {
#pragma unroll
                for (int j = 0; j < 4; ++j) {
                    const int gm = rbase + m * 16 + j;
                    outF[(size_t)gm * DM + gn] = acc[m][n][j];
                }
            }
        }
    }
}

// ---------------- RoPE (in-place on Q and K, [B,H,S,64] bf16) ----------------
__global__ void rope_kernel(bf16_t* __restrict__ Q, bf16_t* __restrict__ Kb,
                            const int* __restrict__ pos, int total) {
    int idx = blockIdx.x * blockDim.x + threadIdx.x;
    if (idx >= total) return;
    const int j = idx & 31;
    const int s = (idx >> 5) & (S_DIM - 1);
    const float p = (float)pos[s];
    const float freq = exp2f((float)j * (-13.287712379549449f / 32.0f));
    const float ang = p * freq;
    const float sn = sinf(ang), cs = cosf(ang);
    const size_t base = ((size_t)(idx >> 5) << 6) + (size_t)(j * 2);
    const float q1 = (float)Q[base], q2 = (float)Q[base + 1];
    Q[base]     = (__bf16)(q1 * cs - q2 * sn);
    Q[base + 1] = (__bf16)(q1 * sn + q2 * cs);
    const float k1 = (float)Kb[base], k2 = (float)Kb[base + 1];
    Kb[base]     = (__bf16)(k1 * cs - k2 * sn);
    Kb[base + 1] = (__bf16)(k1 * sn + k2 * cs);
}

// ---------------- causal flash attention ----------------
// 4 waves/block, each wave owns a 16-row q-tile; KV tiles of 64.
// Swapped QK^T: s = mfma(K, Q) -> D[kv][q], q = lane&15 (one q-row per lane).
// PV as O^T = mfma(Vt, P): D[d][q]. No __syncthreads (per-wave P_lds slice).
__global__ __launch_bounds__(256)
void attn_kernel(const bf16_t* __restrict__ Q, const bf16_t* __restrict__ Kg,
                 const bf16_t* __restrict__ Vt, bf16_t* __restrict__ O) {
    constexpr int PSTR = 72;  // padded: write 2-way free, b128 read uniform
    __shared__ bf16_t P_lds[4][16 * PSTR];
    const int t = threadIdx.x;
    const int lane = t & 63;
    const int w = t >> 6;
    constexpr int nQ = S_DIM / 64;  // 32 q-blocks of 64 rows
    const int bh = blockIdx.x / nQ;
    const int qi = blockIdx.x % nQ;
    const int q0w = (nQ - 1 - qi) * 64 + w * 16;  // reversed: heavy blocks first
    const int b = bh >> 4, h = bh & 15;
    const int rr = lane & 15;
    const int hi = lane >> 4;

    const bf16_t* Qp  = Q  + ((size_t)bh * S_DIM + q0w) * DK;
    const bf16_t* Kp0 = Kg + (size_t)bh * S_DIM * DK;
    const bf16_t* Vp  = Vt + (size_t)bh * DK * S_DIM;
    bf16_t* Pw = P_lds[w];

    // Q fragments (B-operand): row = rr (q), k = c*32 + hi*8; fold 1/8 exactly
    bf16x8 qf[2];
    qf[0] = *reinterpret_cast<const bf16x8*>(&Qp[rr * DK + hi * 8]);
    qf[1] = *reinterpret_cast<const bf16x8*>(&Qp[rr * DK + 32 + hi * 8]);
#pragma unroll
    for (int i = 0; i < 8; ++i) {
        qf[0][i] = (__bf16)((float)qf[0][i] * 0.125f);
        qf[1][i] = (__bf16)((float)qf[1][i] * 0.125f);
    }

    f32x4 o[4] = {};          // o[db][j]: d = db*16 + hi*4 + j, for q = rr
    float m = -INFINITY, l = 0.0f;
    const float L2E = 1.4426950408889634f;

    const int nt = (q0w + 79) >> 6;  // 64-kv tiles covering [0, q0w+16)
    for (int tt = 0; tt < nt; ++tt) {
        const int kv0 = tt * 64;

        // QK^T: s[t16] = D[kv = t16*16 + hi*4 + j][q = rr]
        f32x4 s[4] = {};
#pragma unroll
        for (int t16 = 0; t16 < 4; ++t16) {
            const bf16_t* Kr = Kp0 + (size_t)(kv0 + t16 * 16 + rr) * DK;
            bf16x8 kf0 = *reinterpret_cast<const bf16x8*>(&Kr[hi * 8]);
            bf16x8 kf1 = *reinterpret_cast<const bf16x8*>(&Kr[32 + hi * 8]);
            s[t16] = MFMA(kf0, qf[0], s[t16]);
            s[t16] = MFMA(kf1, qf[1], s[t16]);
        }

        // causal mask — wave-uniform skip for fully-unmasked tiles
        if (kv0 + 63 > q0w) {
            const int qg = q0w + rr;
#pragma unroll
            for (int t16 = 0; t16 < 4; ++t16)
#pragma unroll
                for (int j = 0; j < 4; ++j)
                    if (kv0 + t16 * 16 + hi * 4 + j > qg) s[t16][j] = -INFINITY;
        }

        // per-q max: in-register + 2 shuffles (hi groups)
        float mloc = s[0][0];
#pragma unroll
        for (int t16 = 0; t16 < 4; ++t16)
#pragma unroll
            for (int j = 0; j < 4; ++j) mloc = fmaxf(mloc, s[t16][j]);
        mloc = fmaxf(mloc, __shfl_xor(mloc, 16));
        mloc = fmaxf(mloc, __shfl_xor(mloc, 32));
        const float mnew = fmaxf(m, mloc);
        if (__any(mnew > m)) {
            const float scale = exp2f((m - mnew) * L2E);
            l *= scale;
#pragma unroll
            for (int db = 0; db < 4; ++db)
#pragma unroll
                for (int j = 0; j < 4; ++j) o[db][j] *= scale;
            m = mnew;
        }

        // P = exp(s - m), accumulate row-sum, stash bf16 P in LDS [q][kv]
        float psum = 0.0f;
#pragma unroll
        for (int t16 = 0; t16 < 4; ++t16) {
            bf16x4 pb;
#pragma unroll
            for (int j = 0; j < 4; ++j) {
                const float p = exp2f((s[t16][j] - m) * L2E);
                psum += p;
                pb[j] = (__bf16)p;
            }
            *reinterpret_cast<bf16x4*>(&Pw[rr * PSTR + t16 * 16 + hi * 4]) = pb;
        }
        psum += __shfl_xor(psum, 16);
        psum += __shfl_xor(psum, 32);
        l += psum;

        // PV: O^T[d][q] += Vt[d][kv] * P[q][kv]
        bf16x8 pf0 = *reinterpret_cast<const bf16x8*>(&Pw[rr * PSTR + hi * 8]);
        bf16x8 pf1 = *reinterpret_cast<const bf16x8*>(&Pw[rr * PSTR + 32 + hi * 8]);
#pragma unroll
        for (int db = 0; db < 4; ++db) {
            const bf16_t* Vr = Vp + (size_t)(db * 16 + rr) * S_DIM + kv0;
            bf16x8 vf0 = *reinterpret_cast<const bf16x8*>(&Vr[hi * 8]);
            bf16x8 vf1 = *reinterpret_cast<const bf16x8*>(&Vr[32 + hi * 8]);
            o[db] = MFMA(vf0, pf0, o[db]);
            o[db] = MFMA(vf1, pf1, o[db]);
        }
    }

    const float linv = 1.0f / l;
#pragma unroll
    for (int db = 0; db < 4; ++db) {
        bf16x4 ov;
#pragma unroll
        for (int j = 0; j < 4; ++j) ov[j] = (__bf16)(o[db][j] * linv);
        *reinterpret_cast<bf16x4*>(
            &O[((size_t)(b * S_DIM + q0w + rr)) * DM + h * DK + db * 16 + hi * 4]) = ov;
    }
}

extern "C" void kernel_launch(void* const* d_in, const int* in_sizes, int n_in,
                              void* d_out, int out_size, void* d_ws, size_t ws_size,
                              hipStream_t stream) {
    const float* x  = (const float*)d_in[0];
    const float* Wq = (const float*)d_in[1];
    const float* Wk = (const float*)d_in[2];
    const float* Wv = (const float*)d_in[3];
    const float* Wo = (const float*)d_in[4];
    const int* pos  = (const int*)d_in[5];
    float* out = (float*)d_out;

    char* ws = (char*)d_ws;
    bf16_t* xb  = (bf16_t*)(ws);
    bf16_t* Wqb = (bf16_t*)(ws + (8u << 20));
    bf16_t* Wkb = (bf16_t*)(ws + (10u << 20));
    bf16_t* Wvb = (bf16_t*)(ws + (12u << 20));
    bf16_t* Wob = (bf16_t*)(ws + (14u << 20));
    bf16_t* Qb  = (bf16_t*)(ws + (16u << 20));
    bf16_t* Kb  = (bf16_t*)(ws + (24u << 20));
    bf16_t* Vtb = (bf16_t*)(ws + (32u << 20));
    bf16_t* Ab  = (bf16_t*)(ws);  // reuse xb region after QKV GEMM

    const int NX = B_DIM * S_DIM * DM;
    const int NW = DM * DM;

    cvt_kernel<<<NX / 1024, 256, 0, stream>>>(x, xb, NX);
    cvt4_kernel<<<dim3(NW / 1024, 4), 256, 0, stream>>>(Wq, Wk, Wv, Wo,
                                                        Wqb, Wkb, Wvb, Wob, NW);

    gemm_bt<0><<<dim3(32, 8, 3), 256, 0, stream>>>(xb, Wqb, Wkb, Wvb, Qb, Kb, Vtb, nullptr);

    const int total_pairs = B_DIM * H_DIM * S_DIM * 32;
    rope_kernel<<<total_pairs / 256, 256, 0, stream>>>(Qb, Kb, pos, total_pairs);

    attn_kernel<<<B_DIM * H_DIM * (S_DIM / 64), 256, 0, stream>>>(Qb, Kb, Vtb, Ab);

    gemm_bt<1><<<dim3(32, 8, 1), 256, 0, stream>>>(Ab, Wob, nullptr, nullptr,
                                                   nullptr, nullptr, nullptr, out);
}

// Round 3
// 174.975 us; speedup vs baseline: 1.7925x; 1.7602x over previous
//
#include <hip/hip_runtime.h>
#include <hip/hip_bf16.h>
#include <math.h>

typedef __bf16 bf16_t;
typedef __attribute__((ext_vector_type(8))) __bf16 bf16x8;
typedef __attribute__((ext_vector_type(4))) __bf16 bf16x4;
typedef __attribute__((ext_vector_type(4))) float f32x4;

#define B_DIM 2
#define S_DIM 2048
#define H_DIM 16
#define DK 64
#define DM 1024
#define KDIM 1024

#define MFMA(a, b, c) __builtin_amdgcn_mfma_f32_16x16x32_bf16((a), (b), (c), 0, 0, 0)

__device__ __forceinline__ void gload_lds16(const bf16_t* g, bf16_t* l) {
    __builtin_amdgcn_global_load_lds(
        (const __attribute__((address_space(1))) void*)g,
        (__attribute__((address_space(3))) void*)l, 16, 0, 0);
}

// ---------------- fp32 -> bf16 convert ----------------
__global__ void cvt_kernel(const float* __restrict__ src, bf16_t* __restrict__ dst, int n) {
    int i = (blockIdx.x * blockDim.x + threadIdx.x) * 4;
    if (i >= n) return;
    float4 v = *reinterpret_cast<const float4*>(src + i);
    bf16x4 o;
    o[0] = (__bf16)v.x; o[1] = (__bf16)v.y; o[2] = (__bf16)v.z; o[3] = (__bf16)v.w;
    *reinterpret_cast<bf16x4*>(dst + i) = o;
}

__global__ void cvt4_kernel(const float* __restrict__ s0, const float* __restrict__ s1,
                            const float* __restrict__ s2, const float* __restrict__ s3,
                            bf16_t* __restrict__ d0, bf16_t* __restrict__ d1,
                            bf16_t* __restrict__ d2, bf16_t* __restrict__ d3, int n) {
    const float* s; bf16_t* d;
    switch (blockIdx.y) {
        case 0: s = s0; d = d0; break;
        case 1: s = s1; d = d1; break;
        case 2: s = s2; d = d2; break;
        default: s = s3; d = d3; break;
    }
    int i = (blockIdx.x * blockDim.x + threadIdx.x) * 4;
    if (i >= n) return;
    float4 v = *reinterpret_cast<const float4*>(s + i);
    bf16x4 o;
    o[0] = (__bf16)v.x; o[1] = (__bf16)v.y; o[2] = (__bf16)v.z; o[3] = (__bf16)v.w;
    *reinterpret_cast<bf16x4*>(d + i) = o;
}

// ---------------- GEMM: Y[m,n] = sum_k A[m,k] * B[n,k]  (B^T layout) ----------------
template <int MODE>
__global__ __launch_bounds__(256)
void gemm_bt(const bf16_t* __restrict__ A,
             const bf16_t* __restrict__ B0,
             const bf16_t* __restrict__ B1,
             const bf16_t* __restrict__ B2,
             bf16_t* __restrict__ outQ,
             bf16_t* __restrict__ outK,
             bf16_t* __restrict__ outVt,
             float* __restrict__ outF) {
    __shared__ bf16_t As[128 * 32];
    __shared__ bf16_t Bs[128 * 32];

    const int t = threadIdx.x;
    const int z = blockIdx.z;
    const bf16_t* Bm = (MODE == 0) ? (z == 0 ? B0 : (z == 1 ? B1 : B2)) : B0;

    const int m0 = blockIdx.x * 128;
    const int n0 = blockIdx.y * 128;
    const int lane = t & 63;
    const int w = t >> 6;
    const int wr = w >> 1;
    const int wc = w & 1;

    f32x4 acc[4][4] = {};

    const int ar = t >> 2;
    const int ac = (t & 3) * 8;
    const bf16_t* Ag = A + (size_t)m0 * KDIM;
    const bf16_t* Bg = Bm + (size_t)n0 * KDIM;

    const int rr = lane & 15;
    const int ko = (lane >> 4) * 8;

    for (int k0 = 0; k0 < KDIM; k0 += 32) {
        gload_lds16(Ag + (size_t)ar * KDIM + k0 + ac,        &As[t * 8]);
        gload_lds16(Ag + (size_t)(ar + 64) * KDIM + k0 + ac, &As[2048 + t * 8]);
        gload_lds16(Bg + (size_t)ar * KDIM + k0 + ac,        &Bs[t * 8]);
        gload_lds16(Bg + (size_t)(ar + 64) * KDIM + k0 + ac, &Bs[2048 + t * 8]);
        __syncthreads();

        bf16x8 af[4], bfr[4];
#pragma unroll
        for (int m = 0; m < 4; ++m)
            af[m] = *reinterpret_cast<const bf16x8*>(&As[(wr * 64 + m * 16 + rr) * 32 + ko]);
#pragma unroll
        for (int n = 0; n < 4; ++n)
            bfr[n] = *reinterpret_cast<const bf16x8*>(&Bs[(wc * 64 + n * 16 + rr) * 32 + ko]);
#pragma unroll
        for (int m = 0; m < 4; ++m)
#pragma unroll
            for (int n = 0; n < 4; ++n)
                acc[m][n] = MFMA(af[m], bfr[n], acc[m][n]);
        __syncthreads();
    }

    const int rbase = m0 + wr * 64 + (lane >> 4) * 4;
    const int cbase = n0 + wc * 64 + (lane & 15);
#pragma unroll
    for (int m = 0; m < 4; ++m) {
#pragma unroll
        for (int n = 0; n < 4; ++n) {
            const int gn = cbase + n * 16;
            if (MODE == 0) {
                const int h = gn >> 6, d = gn & 63;
                if (z < 2) {
                    bf16_t* dst = (z == 0) ? outQ : outK;
#pragma unroll
                    for (int j = 0; j < 4; ++j) {
                        const int gm = rbase + m * 16 + j;
                        const int b = gm >> 11, s = gm & (S_DIM - 1);
                        dst[(((size_t)(b * H_DIM + h) * S_DIM + s) << 6) + d] = (__bf16)acc[m][n][j];
                    }
                } else {
                    bf16x4 v;
#pragma unroll
                    for (int j = 0; j < 4; ++j) v[j] = (__bf16)acc[m][n][j];
                    const int gm = rbase + m * 16;
                    const int b = gm >> 11, s = gm & (S_DIM - 1);
                    *reinterpret_cast<bf16x4*>(
                        &outVt[((size_t)(b * H_DIM + h) * DK + d) * S_DIM + s]) = v;
                }
            } else {
#pragma unroll
                for (int j = 0; j < 4; ++j) {
                    const int gm = rbase + m * 16 + j;
                    outF[(size_t)gm * DM + gn] = acc[m][n][j];
                }
            }
        }
    }
}

// ---------------- RoPE (in-place on Q and K, [B,H,S,64] bf16) ----------------
__global__ void rope_kernel(bf16_t* __restrict__ Q, bf16_t* __restrict__ Kb,
                            const int* __restrict__ pos, int total) {
    int idx = blockIdx.x * blockDim.x + threadIdx.x;
    if (idx >= total) return;
    const int j = idx & 31;
    const int s = (idx >> 5) & (S_DIM - 1);
    const float p = (float)pos[s];
    const float freq = exp2f((float)j * (-13.287712379549449f / 32.0f));
    const float ang = p * freq;
    const float sn = sinf(ang), cs = cosf(ang);
    const size_t base = ((size_t)(idx >> 5) << 6) + (size_t)(j * 2);
    const float q1 = (float)Q[base], q2 = (float)Q[base + 1];
    Q[base]     = (__bf16)(q1 * cs - q2 * sn);
    Q[base + 1] = (__bf16)(q1 * sn + q2 * cs);
    const float k1 = (float)Kb[base], k2 = (float)Kb[base + 1];
    Kb[base]     = (__bf16)(k1 * cs - k2 * sn);
    Kb[base + 1] = (__bf16)(k1 * sn + k2 * cs);
}

// ---------------- causal flash attention v3 ----------------
// Block = 4 waves = one 64-row q-block (wave w: rows q0+w*16..+15).
// K/V tiles (64 kv) staged in LDS via global_load_lds, double-buffered,
// XOR-swizzled (pre-swizzled global source, swizzled LDS read).
// Swapped QK^T: s = mfma(K,Q) -> lane owns one q-row. PV: O^T = mfma(Vt,P).
__global__ __launch_bounds__(256)
void attn_kernel(const bf16_t* __restrict__ Q, const bf16_t* __restrict__ Kg,
                 const bf16_t* __restrict__ Vt, bf16_t* __restrict__ O) {
    constexpr int PSTR = 72;
    __shared__ bf16_t Ks[2][64 * 64];
    __shared__ bf16_t Vs[2][64 * 64];
    __shared__ bf16_t P_lds[4][16 * PSTR];

    const int t = threadIdx.x;
    const int lane = t & 63;
    const int w = t >> 6;
    constexpr int nQ = S_DIM / 64;  // 32 q-blocks
    const int bh = blockIdx.x / nQ;
    const int qi = blockIdx.x % nQ;
    const int qb = nQ - 1 - qi;     // heavy blocks first
    const int q0 = qb * 64;
    const int q0w = q0 + w * 16;
    const int b = bh >> 4, h = bh & 15;
    const int rr = lane & 15;
    const int hi = lane >> 4;

    const bf16_t* Qp  = Q  + ((size_t)bh * S_DIM + q0w) * DK;
    const bf16_t* Kbh = Kg + (size_t)bh * S_DIM * DK;
    const bf16_t* Vbh = Vt + (size_t)bh * DK * S_DIM;   // [d][s]
    bf16_t* Pw = P_lds[w];

    // staging: 512 x 16B chunks per 8KB tile; thread t does chunks t and t+256.
    // LDS dest linear (i*16B); global source pre-swizzled: col ^= (row&7)*8 elems.
    const int i0 = t, i1 = t + 256;
    const int r0 = i0 >> 3, c0 = ((i0 & 7) ^ (r0 & 7)) * 8;
    const int r1 = i1 >> 3, c1 = ((i1 & 7) ^ (r1 & 7)) * 8;

    // Q fragments (B-operand), fold 1/8 exactly
    bf16x8 qf[2];
    qf[0] = *reinterpret_cast<const bf16x8*>(&Qp[rr * DK + hi * 8]);
    qf[1] = *reinterpret_cast<const bf16x8*>(&Qp[rr * DK + 32 + hi * 8]);
#pragma unroll
    for (int i = 0; i < 8; ++i) {
        qf[0][i] = (__bf16)((float)qf[0][i] * 0.125f);
        qf[1][i] = (__bf16)((float)qf[1][i] * 0.125f);
    }

    f32x4 o[4] = {};
    float m = -INFINITY, l = 0.0f;
    const float L2E = 1.4426950408889634f;

    const int nt = qb + 1;  // 64-kv tiles

    // prologue: stage tile 0 into buf 0
    gload_lds16(Kbh + (size_t)r0 * DK + c0, &Ks[0][i0 * 8]);
    gload_lds16(Kbh + (size_t)r1 * DK + c1, &Ks[0][i1 * 8]);
    gload_lds16(Vbh + (size_t)r0 * S_DIM + c0, &Vs[0][i0 * 8]);
    gload_lds16(Vbh + (size_t)r1 * S_DIM + c1, &Vs[0][i1 * 8]);
    __syncthreads();

    int cur = 0;
    for (int tt = 0; tt < nt; ++tt) {
        if (tt + 1 < nt) {
            const int kv1 = (tt + 1) * 64;
            gload_lds16(Kbh + (size_t)(kv1 + r0) * DK + c0, &Ks[cur ^ 1][i0 * 8]);
            gload_lds16(Kbh + (size_t)(kv1 + r1) * DK + c1, &Ks[cur ^ 1][i1 * 8]);
            gload_lds16(Vbh + (size_t)r0 * S_DIM + kv1 + c0, &Vs[cur ^ 1][i0 * 8]);
            gload_lds16(Vbh + (size_t)r1 * S_DIM + kv1 + c1, &Vs[cur ^ 1][i1 * 8]);
        }
        const bf16_t* Kc = Ks[cur];
        const bf16_t* Vc = Vs[cur];

        // QK^T: s[t16][j] = S[kv = t16*16 + hi*4 + j][q = rr]
        f32x4 s[4] = {};
#pragma unroll
        for (int t16 = 0; t16 < 4; ++t16) {
            const int r = t16 * 16 + rr;
            const int sw = (r & 7) * 8;
            bf16x8 kf0 = *reinterpret_cast<const bf16x8*>(&Kc[r * 64 + ((hi * 8) ^ sw)]);
            bf16x8 kf1 = *reinterpret_cast<const bf16x8*>(&Kc[r * 64 + ((32 + hi * 8) ^ sw)]);
            s[t16] = MFMA(kf0, qf[0], s[t16]);
            s[t16] = MFMA(kf1, qf[1], s[t16]);
        }

        // causal mask — only the last tile can touch the diagonal
        if (tt == nt - 1) {
            const int kv0 = tt * 64;
            const int qg = q0w + rr;
#pragma unroll
            for (int t16 = 0; t16 < 4; ++t16)
#pragma unroll
                for (int j = 0; j < 4; ++j)
                    if (kv0 + t16 * 16 + hi * 4 + j > qg) s[t16][j] = -INFINITY;
        }

        // per-q max: in-register + 2 shuffles
        float mloc = s[0][0];
#pragma unroll
        for (int t16 = 0; t16 < 4; ++t16)
#pragma unroll
            for (int j = 0; j < 4; ++j) mloc = fmaxf(mloc, s[t16][j]);
        mloc = fmaxf(mloc, __shfl_xor(mloc, 16));
        mloc = fmaxf(mloc, __shfl_xor(mloc, 32));
        const float mnew = fmaxf(m, mloc);
        if (__any(mnew > m)) {
            const float scale = exp2f((m - mnew) * L2E);
            l *= scale;
#pragma unroll
            for (int db = 0; db < 4; ++db)
#pragma unroll
                for (int j = 0; j < 4; ++j) o[db][j] *= scale;
            m = mnew;
        }

        // P = exp(s - m), row-sum, stash bf16 P in LDS [q][kv]
        float psum = 0.0f;
#pragma unroll
        for (int t16 = 0; t16 < 4; ++t16) {
            bf16x4 pb;
#pragma unroll
            for (int j = 0; j < 4; ++j) {
                const float p = exp2f((s[t16][j] - m) * L2E);
                psum += p;
                pb[j] = (__bf16)p;
            }
            *reinterpret_cast<bf16x4*>(&Pw[rr * PSTR + t16 * 16 + hi * 4]) = pb;
        }
        psum += __shfl_xor(psum, 16);
        psum += __shfl_xor(psum, 32);
        l += psum;

        // PV: O^T[d][q] += Vt[d][kv] * P[q][kv]
        bf16x8 pf0 = *reinterpret_cast<const bf16x8*>(&Pw[rr * PSTR + hi * 8]);
        bf16x8 pf1 = *reinterpret_cast<const bf16x8*>(&Pw[rr * PSTR + 32 + hi * 8]);
#pragma unroll
        for (int db = 0; db < 4; ++db) {
            const int vr = db * 16 + rr;
            const int sw = (vr & 7) * 8;
            bf16x8 vf0 = *reinterpret_cast<const bf16x8*>(&Vc[vr * 64 + ((hi * 8) ^ sw)]);
            bf16x8 vf1 = *reinterpret_cast<const bf16x8*>(&Vc[vr * 64 + ((32 + hi * 8) ^ sw)]);
            o[db] = MFMA(vf0, pf0, o[db]);
            o[db] = MFMA(vf1, pf1, o[db]);
        }
        __syncthreads();
        cur ^= 1;
    }

    const float linv = 1.0f / l;
#pragma unroll
    for (int db = 0; db < 4; ++db) {
        bf16x4 ov;
#pragma unroll
        for (int j = 0; j < 4; ++j) ov[j] = (__bf16)(o[db][j] * linv);
        *reinterpret_cast<bf16x4*>(
            &O[((size_t)(b * S_DIM + q0w + rr)) * DM + h * DK + db * 16 + hi * 4]) = ov;
    }
}

extern "C" void kernel_launch(void* const* d_in, const int* in_sizes, int n_in,
                              void* d_out, int out_size, void* d_ws, size_t ws_size,
                              hipStream_t stream) {
    const float* x  = (const float*)d_in[0];
    const float* Wq = (const float*)d_in[1];
    const float* Wk = (const float*)d_in[2];
    const float* Wv = (const float*)d_in[3];
    const float* Wo = (const float*)d_in[4];
    const int* pos  = (const int*)d_in[5];
    float* out = (float*)d_out;

    char* ws = (char*)d_ws;
    bf16_t* xb  = (bf16_t*)(ws);
    bf16_t* Wqb = (bf16_t*)(ws + (8u << 20));
    bf16_t* Wkb = (bf16_t*)(ws + (10u << 20));
    bf16_t* Wvb = (bf16_t*)(ws + (12u << 20));
    bf16_t* Wob = (bf16_t*)(ws + (14u << 20));
    bf16_t* Qb  = (bf16_t*)(ws + (16u << 20));
    bf16_t* Kb  = (bf16_t*)(ws + (24u << 20));
    bf16_t* Vtb = (bf16_t*)(ws + (32u << 20));
    bf16_t* Ab  = (bf16_t*)(ws);  // reuse xb region after QKV GEMM

    const int NX = B_DIM * S_DIM * DM;
    const int NW = DM * DM;

    cvt_kernel<<<NX / 1024, 256, 0, stream>>>(x, xb, NX);
    cvt4_kernel<<<dim3(NW / 1024, 4), 256, 0, stream>>>(Wq, Wk, Wv, Wo,
                                                        Wqb, Wkb, Wvb, Wob, NW);

    gemm_bt<0><<<dim3(32, 8, 3), 256, 0, stream>>>(xb, Wqb, Wkb, Wvb, Qb, Kb, Vtb, nullptr);

    const int total_pairs = B_DIM * H_DIM * S_DIM * 32;
    rope_kernel<<<total_pairs / 256, 256, 0, stream>>>(Qb, Kb, pos, total_pairs);

    attn_kernel<<<B_DIM * H_DIM * (S_DIM / 64), 256, 0, stream>>>(Qb, Kb, Vtb, Ab);

    gemm_bt<1><<<dim3(32, 8, 1), 256, 0, stream>>>(Ab, Wob, nullptr, nullptr,
                                                   nullptr, nullptr, nullptr, out);
}

// Round 4
// 173.820 us; speedup vs baseline: 1.8044x; 1.0066x over previous
//
#include <hip/hip_runtime.h>
#include <hip/hip_bf16.h>
#include <math.h>

typedef __bf16 bf16_t;
typedef __attribute__((ext_vector_type(8))) __bf16 bf16x8;
typedef __attribute__((ext_vector_type(4))) __bf16 bf16x4;
typedef __attribute__((ext_vector_type(4))) float f32x4;

#define B_DIM 2
#define S_DIM 2048
#define H_DIM 16
#define DK 64
#define DM 1024
#define KDIM 1024

#define MFMA(a, b, c) __builtin_amdgcn_mfma_f32_16x16x32_bf16((a), (b), (c), 0, 0, 0)

__device__ __forceinline__ void gload_lds16(const bf16_t* g, bf16_t* l) {
    __builtin_amdgcn_global_load_lds(
        (const __attribute__((address_space(1))) void*)g,
        (__attribute__((address_space(3))) void*)l, 16, 0, 0);
}

// ---------------- fp32 -> bf16 convert ----------------
__global__ void cvt_kernel(const float* __restrict__ src, bf16_t* __restrict__ dst, int n) {
    int i = (blockIdx.x * blockDim.x + threadIdx.x) * 4;
    if (i >= n) return;
    float4 v = *reinterpret_cast<const float4*>(src + i);
    bf16x4 o;
    o[0] = (__bf16)v.x; o[1] = (__bf16)v.y; o[2] = (__bf16)v.z; o[3] = (__bf16)v.w;
    *reinterpret_cast<bf16x4*>(dst + i) = o;
}

__global__ void cvt4_kernel(const float* __restrict__ s0, const float* __restrict__ s1,
                            const float* __restrict__ s2, const float* __restrict__ s3,
                            bf16_t* __restrict__ d0, bf16_t* __restrict__ d1,
                            bf16_t* __restrict__ d2, bf16_t* __restrict__ d3, int n) {
    const float* s; bf16_t* d;
    switch (blockIdx.y) {
        case 0: s = s0; d = d0; break;
        case 1: s = s1; d = d1; break;
        case 2: s = s2; d = d2; break;
        default: s = s3; d = d3; break;
    }
    int i = (blockIdx.x * blockDim.x + threadIdx.x) * 4;
    if (i >= n) return;
    float4 v = *reinterpret_cast<const float4*>(s + i);
    bf16x4 o;
    o[0] = (__bf16)v.x; o[1] = (__bf16)v.y; o[2] = (__bf16)v.z; o[3] = (__bf16)v.w;
    *reinterpret_cast<bf16x4*>(d + i) = o;
}

// ---------------- GEMM: Y[m,n] = sum_k A[m,k] * B[n,k]  (B^T layout) ----------------
template <int MODE>
__global__ __launch_bounds__(256)
void gemm_bt(const bf16_t* __restrict__ A,
             const bf16_t* __restrict__ B0,
             const bf16_t* __restrict__ B1,
             const bf16_t* __restrict__ B2,
             bf16_t* __restrict__ outQ,
             bf16_t* __restrict__ outK,
             bf16_t* __restrict__ outVt,
             float* __restrict__ outF) {
    __shared__ bf16_t As[128 * 32];
    __shared__ bf16_t Bs[128 * 32];

    const int t = threadIdx.x;
    const int z = blockIdx.z;
    const bf16_t* Bm = (MODE == 0) ? (z == 0 ? B0 : (z == 1 ? B1 : B2)) : B0;

    const int m0 = blockIdx.x * 128;
    const int n0 = blockIdx.y * 128;
    const int lane = t & 63;
    const int w = t >> 6;
    const int wr = w >> 1;
    const int wc = w & 1;

    f32x4 acc[4][4] = {};

    const int ar = t >> 2;
    const int ac = (t & 3) * 8;
    const bf16_t* Ag = A + (size_t)m0 * KDIM;
    const bf16_t* Bg = Bm + (size_t)n0 * KDIM;

    const int rr = lane & 15;
    const int ko = (lane >> 4) * 8;

    for (int k0 = 0; k0 < KDIM; k0 += 32) {
        gload_lds16(Ag + (size_t)ar * KDIM + k0 + ac,        &As[t * 8]);
        gload_lds16(Ag + (size_t)(ar + 64) * KDIM + k0 + ac, &As[2048 + t * 8]);
        gload_lds16(Bg + (size_t)ar * KDIM + k0 + ac,        &Bs[t * 8]);
        gload_lds16(Bg + (size_t)(ar + 64) * KDIM + k0 + ac, &Bs[2048 + t * 8]);
        __syncthreads();

        bf16x8 af[4], bfr[4];
#pragma unroll
        for (int m = 0; m < 4; ++m)
            af[m] = *reinterpret_cast<const bf16x8*>(&As[(wr * 64 + m * 16 + rr) * 32 + ko]);
#pragma unroll
        for (int n = 0; n < 4; ++n)
            bfr[n] = *reinterpret_cast<const bf16x8*>(&Bs[(wc * 64 + n * 16 + rr) * 32 + ko]);
#pragma unroll
        for (int m = 0; m < 4; ++m)
#pragma unroll
            for (int n = 0; n < 4; ++n)
                acc[m][n] = MFMA(af[m], bfr[n], acc[m][n]);
        __syncthreads();
    }

    const int rbase = m0 + wr * 64 + (lane >> 4) * 4;
    const int cbase = n0 + wc * 64 + (lane & 15);
#pragma unroll
    for (int m = 0; m < 4; ++m) {
#pragma unroll
        for (int n = 0; n < 4; ++n) {
            const int gn = cbase + n * 16;
            if (MODE == 0) {
                const int h = gn >> 6, d = gn & 63;
                if (z < 2) {
                    bf16_t* dst = (z == 0) ? outQ : outK;
#pragma unroll
                    for (int j = 0; j < 4; ++j) {
                        const int gm = rbase + m * 16 + j;
                        const int b = gm >> 11, s = gm & (S_DIM - 1);
                        dst[(((size_t)(b * H_DIM + h) * S_DIM + s) << 6) + d] = (__bf16)acc[m][n][j];
                    }
                } else {
                    bf16x4 v;
#pragma unroll
                    for (int j = 0; j < 4; ++j) v[j] = (__bf16)acc[m][n][j];
                    const int gm = rbase + m * 16;
                    const int b = gm >> 11, s = gm & (S_DIM - 1);
                    *reinterpret_cast<bf16x4*>(
                        &outVt[((size_t)(b * H_DIM + h) * DK + d) * S_DIM + s]) = v;
                }
            } else {
#pragma unroll
                for (int j = 0; j < 4; ++j) {
                    const int gm = rbase + m * 16 + j;
                    outF[(size_t)gm * DM + gn] = acc[m][n][j];
                }
            }
        }
    }
}

// ---------------- RoPE (in-place on Q and K, [B,H,S,64] bf16) ----------------
__global__ void rope_kernel(bf16_t* __restrict__ Q, bf16_t* __restrict__ Kb,
                            const int* __restrict__ pos, int total) {
    int idx = blockIdx.x * blockDim.x + threadIdx.x;
    if (idx >= total) return;
    const int j = idx & 31;
    const int s = (idx >> 5) & (S_DIM - 1);
    const float p = (float)pos[s];
    const float freq = exp2f((float)j * (-13.287712379549449f / 32.0f));
    const float ang = p * freq;
    const float sn = sinf(ang), cs = cosf(ang);
    const size_t base = ((size_t)(idx >> 5) << 6) + (size_t)(j * 2);
    const float q1 = (float)Q[base], q2 = (float)Q[base + 1];
    Q[base]     = (__bf16)(q1 * cs - q2 * sn);
    Q[base + 1] = (__bf16)(q1 * sn + q2 * cs);
    const float k1 = (float)Kb[base], k2 = (float)Kb[base + 1];
    Kb[base]     = (__bf16)(k1 * cs - k2 * sn);
    Kb[base + 1] = (__bf16)(k1 * sn + k2 * cs);
}

// ---------------- causal flash attention v4 ----------------
// Block = 4 waves = one 64-row q-block. K/V tiles (64 kv) in LDS, XOR-swizzled.
// Counted-vmcnt pipeline (T3/T4): K triple-buffered staged pre-barrier,
// V double-buffered staged post-barrier; s_waitcnt vmcnt(2) (never 0 except
// last iter) + raw s_barrier -> loads stay in flight across compute phases.
__global__ __launch_bounds__(256)
void attn_kernel(const bf16_t* __restrict__ Q, const bf16_t* __restrict__ Kg,
                 const bf16_t* __restrict__ Vt, bf16_t* __restrict__ O) {
    constexpr int PSTR = 72;
    __shared__ bf16_t Ks[3][64 * 64];
    __shared__ bf16_t Vs[2][64 * 64];
    __shared__ bf16_t P_lds[4][16 * PSTR];

    const int t = threadIdx.x;
    const int lane = t & 63;
    const int w = t >> 6;
    constexpr int nQ = S_DIM / 64;  // 32 q-blocks
    const int bh = blockIdx.x / nQ;
    const int qi = blockIdx.x % nQ;
    const int qb = nQ - 1 - qi;     // heavy blocks first
    const int q0 = qb * 64;
    const int q0w = q0 + w * 16;
    const int b = bh >> 4, h = bh & 15;
    const int rr = lane & 15;
    const int hi = lane >> 4;

    const bf16_t* Qp  = Q  + ((size_t)bh * S_DIM + q0w) * DK;
    const bf16_t* Kbh = Kg + (size_t)bh * S_DIM * DK;
    const bf16_t* Vbh = Vt + (size_t)bh * DK * S_DIM;   // [d][s]
    bf16_t* Pw = P_lds[w];

    // staging: 512 x 16B chunks per 8KB tile; thread t does chunks t and t+256.
    // LDS dest linear; global source pre-swizzled: col ^= (row&7)*8 elems.
    const int i0 = t, i1 = t + 256;
    const int r0 = i0 >> 3, c0 = ((i0 & 7) ^ (r0 & 7)) * 8;
    const int r1 = i1 >> 3, c1 = ((i1 & 7) ^ (r1 & 7)) * 8;

    // Q fragments (B-operand), fold 1/8 exactly
    bf16x8 qf[2];
    qf[0] = *reinterpret_cast<const bf16x8*>(&Qp[rr * DK + hi * 8]);
    qf[1] = *reinterpret_cast<const bf16x8*>(&Qp[rr * DK + 32 + hi * 8]);
#pragma unroll
    for (int i = 0; i < 8; ++i) {
        qf[0][i] = (__bf16)((float)qf[0][i] * 0.125f);
        qf[1][i] = (__bf16)((float)qf[1][i] * 0.125f);
    }

    f32x4 o[4] = {};
    float m = -INFINITY, l = 0.0f;
    const float L2E = 1.4426950408889634f;

    const int nt = qb + 1;  // 64-kv tiles

    // prologue: stage tile 0 (K buf0, V buf0); no barrier — loop top handles it
    gload_lds16(Kbh + (size_t)r0 * DK + c0, &Ks[0][i0 * 8]);
    gload_lds16(Kbh + (size_t)r1 * DK + c1, &Ks[0][i1 * 8]);
    gload_lds16(Vbh + (size_t)r0 * S_DIM + c0, &Vs[0][i0 * 8]);
    gload_lds16(Vbh + (size_t)r1 * S_DIM + c1, &Vs[0][i1 * 8]);

    for (int tt = 0; tt < nt; ++tt) {
        const int kb = tt % 3, vb = tt & 1;
        // stage K(t+1) pre-barrier (3 bufs make this safe vs lagging waves),
        // then counted wait: only the 2 newest (K(t+1)) may stay in flight.
        if (tt + 1 < nt) {
            const int kv1 = (tt + 1) * 64;
            const int kb1 = (tt + 1) % 3;
            gload_lds16(Kbh + (size_t)(kv1 + r0) * DK + c0, &Ks[kb1][i0 * 8]);
            gload_lds16(Kbh + (size_t)(kv1 + r1) * DK + c1, &Ks[kb1][i1 * 8]);
            asm volatile("s_waitcnt vmcnt(2)" ::: "memory");
        } else {
            asm volatile("s_waitcnt vmcnt(0)" ::: "memory");
        }
        __builtin_amdgcn_s_barrier();
        __builtin_amdgcn_sched_barrier(0);
        // stage V(t+1) post-barrier (2 bufs safe: all waves done with t-1)
        if (tt + 1 < nt) {
            const int kv1 = (tt + 1) * 64;
            const int vb1 = (tt + 1) & 1;
            gload_lds16(Vbh + (size_t)r0 * S_DIM + kv1 + c0, &Vs[vb1][i0 * 8]);
            gload_lds16(Vbh + (size_t)r1 * S_DIM + kv1 + c1, &Vs[vb1][i1 * 8]);
        }
        const bf16_t* Kc = Ks[kb];
        const bf16_t* Vc = Vs[vb];

        // QK^T: s[t16][j] = S[kv = t16*16 + hi*4 + j][q = rr]
        f32x4 s[4] = {};
        __builtin_amdgcn_s_setprio(1);
#pragma unroll
        for (int t16 = 0; t16 < 4; ++t16) {
            const int r = t16 * 16 + rr;
            const int sw = (r & 7) * 8;
            bf16x8 kf0 = *reinterpret_cast<const bf16x8*>(&Kc[r * 64 + ((hi * 8) ^ sw)]);
            bf16x8 kf1 = *reinterpret_cast<const bf16x8*>(&Kc[r * 64 + ((32 + hi * 8) ^ sw)]);
            s[t16] = MFMA(kf0, qf[0], s[t16]);
            s[t16] = MFMA(kf1, qf[1], s[t16]);
        }
        __builtin_amdgcn_s_setprio(0);

        // causal mask — only the last tile touches the diagonal
        if (tt == nt - 1) {
            const int kv0 = tt * 64;
            const int qg = q0w + rr;
#pragma unroll
            for (int t16 = 0; t16 < 4; ++t16)
#pragma unroll
                for (int j = 0; j < 4; ++j)
                    if (kv0 + t16 * 16 + hi * 4 + j > qg) s[t16][j] = -INFINITY;
        }

        // per-q max: in-register + 2 shuffles
        float mloc = s[0][0];
#pragma unroll
        for (int t16 = 0; t16 < 4; ++t16)
#pragma unroll
            for (int j = 0; j < 4; ++j) mloc = fmaxf(mloc, s[t16][j]);
        mloc = fmaxf(mloc, __shfl_xor(mloc, 16));
        mloc = fmaxf(mloc, __shfl_xor(mloc, 32));
        // defer-max (T13): only rescale when max grew by > 8 (P bounded by e^8)
        if (__any(mloc - m > 8.0f)) {
            const float mnew = fmaxf(m, mloc);
            const float scale = exp2f((m - mnew) * L2E);
            l *= scale;
#pragma unroll
            for (int db = 0; db < 4; ++db)
#pragma unroll
                for (int j = 0; j < 4; ++j) o[db][j] *= scale;
            m = mnew;
        }

        // P = exp(s - m), row-sum, stash bf16 P in LDS [q][kv]
        float psum = 0.0f;
#pragma unroll
        for (int t16 = 0; t16 < 4; ++t16) {
            bf16x4 pb;
#pragma unroll
            for (int j = 0; j < 4; ++j) {
                const float p = exp2f((s[t16][j] - m) * L2E);
                psum += p;
                pb[j] = (__bf16)p;
            }
            *reinterpret_cast<bf16x4*>(&Pw[rr * PSTR + t16 * 16 + hi * 4]) = pb;
        }
        psum += __shfl_xor(psum, 16);
        psum += __shfl_xor(psum, 32);
        l += psum;

        // PV: O^T[d][q] += Vt[d][kv] * P[q][kv]
        bf16x8 pf0 = *reinterpret_cast<const bf16x8*>(&Pw[rr * PSTR + hi * 8]);
        bf16x8 pf1 = *reinterpret_cast<const bf16x8*>(&Pw[rr * PSTR + 32 + hi * 8]);
        __builtin_amdgcn_s_setprio(1);
#pragma unroll
        for (int db = 0; db < 4; ++db) {
            const int vr = db * 16 + rr;
            const int sw = (vr & 7) * 8;
            bf16x8 vf0 = *reinterpret_cast<const bf16x8*>(&Vc[vr * 64 + ((hi * 8) ^ sw)]);
            bf16x8 vf1 = *reinterpret_cast<const bf16x8*>(&Vc[vr * 64 + ((32 + hi * 8) ^ sw)]);
            o[db] = MFMA(vf0, pf0, o[db]);
            o[db] = MFMA(vf1, pf1, o[db]);
        }
        __builtin_amdgcn_s_setprio(0);
    }

    const float linv = 1.0f / l;
#pragma unroll
    for (int db = 0; db < 4; ++db) {
        bf16x4 ov;
#pragma unroll
        for (int j = 0; j < 4; ++j) ov[j] = (__bf16)(o[db][j] * linv);
        *reinterpret_cast<bf16x4*>(
            &O[((size_t)(b * S_DIM + q0w + rr)) * DM + h * DK + db * 16 + hi * 4]) = ov;
    }
}

extern "C" void kernel_launch(void* const* d_in, const int* in_sizes, int n_in,
                              void* d_out, int out_size, void* d_ws, size_t ws_size,
                              hipStream_t stream) {
    const float* x  = (const float*)d_in[0];
    const float* Wq = (const float*)d_in[1];
    const float* Wk = (const float*)d_in[2];
    const float* Wv = (const float*)d_in[3];
    const float* Wo = (const float*)d_in[4];
    const int* pos  = (const int*)d_in[5];
    float* out = (float*)d_out;

    char* ws = (char*)d_ws;
    bf16_t* xb  = (bf16_t*)(ws);
    bf16_t* Wqb = (bf16_t*)(ws + (8u << 20));
    bf16_t* Wkb = (bf16_t*)(ws + (10u << 20));
    bf16_t* Wvb = (bf16_t*)(ws + (12u << 20));
    bf16_t* Wob = (bf16_t*)(ws + (14u << 20));
    bf16_t* Qb  = (bf16_t*)(ws + (16u << 20));
    bf16_t* Kb  = (bf16_t*)(ws + (24u << 20));
    bf16_t* Vtb = (bf16_t*)(ws + (32u << 20));
    bf16_t* Ab  = (bf16_t*)(ws);  // reuse xb region after QKV GEMM

    const int NX = B_DIM * S_DIM * DM;
    const int NW = DM * DM;

    cvt_kernel<<<NX / 1024, 256, 0, stream>>>(x, xb, NX);
    cvt4_kernel<<<dim3(NW / 1024, 4), 256, 0, stream>>>(Wq, Wk, Wv, Wo,
                                                        Wqb, Wkb, Wvb, Wob, NW);

    gemm_bt<0><<<dim3(32, 8, 3), 256, 0, stream>>>(xb, Wqb, Wkb, Wvb, Qb, Kb, Vtb, nullptr);

    const int total_pairs = B_DIM * H_DIM * S_DIM * 32;
    rope_kernel<<<total_pairs / 256, 256, 0, stream>>>(Qb, Kb, pos, total_pairs);

    attn_kernel<<<B_DIM * H_DIM * (S_DIM / 64), 256, 0, stream>>>(Qb, Kb, Vtb, Ab);

    gemm_bt<1><<<dim3(32, 8, 1), 256, 0, stream>>>(Ab, Wob, nullptr, nullptr,
                                                   nullptr, nullptr, nullptr, out);
}